// Round 1
// baseline (1436.759 us; speedup 1.0000x reference)
//
#include <hip/hip_runtime.h>

// Problem constants (Switch-Transformer tokens-choose router)
constexpr int Gn = 4;      // groups
constexpr int Tn = 4096;   // tokens per group
constexpr int Dn = 2048;   // d_model
constexpr int En = 64;     // experts
constexpr int Cn = 128;    // expert capacity
constexpr int NT = Gn * Tn;               // 16384 tokens total
constexpr size_t NDC = (size_t)NT * En * Cn; // 134217728 elements per [g,t,e,c] tensor

// ---------------------------------------------------------------------------
// Kernel 0: zero the fp64 accumulators (sumP[256] + zsum[1])
// ---------------------------------------------------------------------------
__global__ void k_zero(double* acc) {
    int i = threadIdx.x;
    if (i < Gn * En + 1) acc[i] = 0.0;
}

// ---------------------------------------------------------------------------
// Kernel 1: fp64-accumulated router GEMM + softmax + top-2 + stats.
// Block = 256 threads = 4 waves; block handles 16 consecutive tokens.
// Wave r (lane = expert) handles tokens r, r+4, r+8, r+12 of the block.
// ---------------------------------------------------------------------------
__global__ __launch_bounds__(256) void k_gemm(
    const float* __restrict__ x, const float* __restrict__ Wm,
    const float* __restrict__ bias,
    double* __restrict__ gate, int* __restrict__ e1a, int* __restrict__ e2a,
    float* __restrict__ p1a, float* __restrict__ p2a,
    double* __restrict__ sumP, double* __restrict__ zsum)
{
    __shared__ float xs[16][64];
    __shared__ float sW[64][64];
    __shared__ double spart[4][64];
    __shared__ double zpart[4];

    const int tid  = threadIdx.x;
    const int lane = tid & 63;
    const int wave = tid >> 6;
    const int tok0 = blockIdx.x * 16;
    const int g    = blockIdx.x >> 8;   // 256 blocks per group

    double acc[4] = {0.0, 0.0, 0.0, 0.0};

    for (int d0 = 0; d0 < Dn; d0 += 64) {
        // stage x tile: 16 tokens x 64 dims
        {
            int row = tid >> 4;
            int col = (tid & 15) * 4;
            *(float4*)&xs[row][col] =
                *(const float4*)(x + (size_t)(tok0 + row) * Dn + d0 + col);
        }
        // stage W tile: rows d0..d0+63, all 64 experts (contiguous 16 KB)
        {
            const float4* src = (const float4*)(Wm + (size_t)d0 * En);
            float4* dst = (float4*)&sW[0][0];
            dst[tid]       = src[tid];
            dst[tid + 256] = src[tid + 256];
            dst[tid + 512] = src[tid + 512];
            dst[tid + 768] = src[tid + 768];
        }
        __syncthreads();

        #pragma unroll 4
        for (int q = 0; q < 16; ++q) {
            float4 x0 = *(const float4*)&xs[wave +  0][q * 4];
            float4 x1 = *(const float4*)&xs[wave +  4][q * 4];
            float4 x2 = *(const float4*)&xs[wave +  8][q * 4];
            float4 x3 = *(const float4*)&xs[wave + 12][q * 4];
            const float* f0 = (const float*)&x0;
            const float* f1 = (const float*)&x1;
            const float* f2 = (const float*)&x2;
            const float* f3 = (const float*)&x3;
            #pragma unroll
            for (int j = 0; j < 4; ++j) {
                double w = (double)sW[q * 4 + j][lane];
                acc[0] += (double)f0[j] * w;
                acc[1] += (double)f1[j] * w;
                acc[2] += (double)f2[j] * w;
                acc[3] += (double)f3[j] * w;
            }
        }
        __syncthreads();
    }

    const double bl = (double)bias[lane];
    double spsum = 0.0, zacc = 0.0;

    #pragma unroll
    for (int i = 0; i < 4; ++i) {
        double l = acc[i] + bl;
        // wave max
        double m = l;
        #pragma unroll
        for (int off = 32; off; off >>= 1) {
            double o = __shfl_xor(m, off);
            m = (o > m) ? o : m;
        }
        double ex = exp(l - m);
        double s = ex;
        #pragma unroll
        for (int off = 32; off; off >>= 1) s += __shfl_xor(s, off);
        double p = ex / s;
        double lse = m + log(s);
        double zt = (l - lse) * (l - lse);
        #pragma unroll
        for (int off = 32; off; off >>= 1) zt += __shfl_xor(zt, off);

        // top-1 (ties -> lower index, matching lax.top_k)
        double pb = p; int ib = lane;
        #pragma unroll
        for (int off = 32; off; off >>= 1) {
            double po = __shfl_xor(pb, off);
            int    io = __shfl_xor(ib, off);
            if (po > pb || (po == pb && io < ib)) { pb = po; ib = io; }
        }
        // top-2
        double pb2 = (lane == ib) ? -1.0 : p; int ib2 = lane;
        #pragma unroll
        for (int off = 32; off; off >>= 1) {
            double po = __shfl_xor(pb2, off);
            int    io = __shfl_xor(ib2, off);
            if (po > pb2 || (po == pb2 && io < ib2)) { pb2 = po; ib2 = io; }
        }

        spsum += p;
        zacc  += zt;   // identical on all lanes; only lane 0 uses it

        if (lane == 0) {
            int tok = tok0 + wave + 4 * i;
            gate[tok] = pb;
            e1a[tok] = ib;
            e2a[tok] = ib2;
            p1a[tok] = (float)pb;
            p2a[tok] = (float)pb2;
        }
    }

    spart[wave][lane] = spsum;
    if (lane == 0) zpart[wave] = zacc;
    __syncthreads();
    if (wave == 0) {
        double v = spart[0][lane] + spart[1][lane] + spart[2][lane] + spart[3][lane];
        atomicAdd(&sumP[g * En + lane], v);
        if (lane == 0)
            atomicAdd(zsum, zpart[0] + zpart[1] + zpart[2] + zpart[3]);
    }
}

// ---------------------------------------------------------------------------
// Kernel 2: per-group bitonic sort of 4096 tokens by (gate desc, idx asc).
// Deterministic total order == stable argsort(-gate).
// ---------------------------------------------------------------------------
__global__ __launch_bounds__(1024) void k_sort(const double* __restrict__ gate,
                                               int* __restrict__ sidx)
{
    __shared__ double key[4096];
    __shared__ int    val[4096];
    const int g = blockIdx.x;
    for (int i = threadIdx.x; i < Tn; i += 1024) {
        key[i] = gate[g * Tn + i];
        val[i] = i;
    }
    __syncthreads();
    for (int k = 2; k <= Tn; k <<= 1) {
        for (int j = k >> 1; j > 0; j >>= 1) {
            for (int i = threadIdx.x; i < Tn; i += 1024) {
                int ixj = i ^ j;
                if (ixj > i) {
                    bool dir = ((i & k) == 0);
                    double ka = key[i], kb = key[ixj];
                    int    va = val[i], vb = val[ixj];
                    // does element at ixj come first in (gate desc, idx asc)?
                    bool bFirst = (kb > ka) || (kb == ka && vb < va);
                    if (bFirst == dir) {
                        key[i] = kb; key[ixj] = ka;
                        val[i] = vb; val[ixj] = va;
                    }
                }
            }
            __syncthreads();
        }
    }
    for (int i = threadIdx.x; i < Tn; i += 1024) sidx[g * Tn + i] = val[i];
}

// ---------------------------------------------------------------------------
// Kernel 3: gather the expert sequence in cumsum order
// (all top-1 choices in sorted order, then all top-2 choices).
// ---------------------------------------------------------------------------
__global__ void k_gather(const int* __restrict__ sidx,
                         const int* __restrict__ e1a, const int* __restrict__ e2a,
                         int* __restrict__ eseq, int* __restrict__ tseq)
{
    int idx = blockIdx.x * 256 + threadIdx.x;   // 0 .. 32767
    int g = idx >> 13;
    int j = idx & 8191;
    int s = (j < Tn) ? j : j - Tn;
    int tok = sidx[g * Tn + s];
    int e = (j < Tn) ? e1a[g * Tn + tok] : e2a[g * Tn + tok];
    eseq[idx] = e;
    tseq[idx] = tok;
}

// ---------------------------------------------------------------------------
// Kernel 4: sequential capacity assignment. One wave per group.
// Ballot-based per-expert matching; lane l owns expert l's running count.
// ---------------------------------------------------------------------------
__global__ __launch_bounds__(64) void k_prio(
    const int* __restrict__ eseq, const int* __restrict__ tseq,
    int* __restrict__ pr1, int* __restrict__ pr2, int* __restrict__ cnt)
{
    const int g = blockIdx.x;
    const int lane = threadIdx.x;
    int base = 0;   // running count for expert == lane

    for (int c = 0; c < 2 * Tn / 64; ++c) {   // 128 chunks of 64 entries
        int j   = c * 64 + lane;
        int e   = eseq[g * 2 * Tn + j];
        int tok = tseq[g * 2 * Tn + j];

        unsigned long long m  = ~0ull;   // entries matching MY entry's expert
        unsigned long long mo = ~0ull;   // entries matching my OWNED expert (=lane)
        #pragma unroll
        for (int bb = 0; bb < 6; ++bb) {
            unsigned long long bal = __ballot((e >> bb) & 1);
            m  &= ((e    >> bb) & 1) ? bal : ~bal;
            mo &= ((lane >> bb) & 1) ? bal : ~bal;
        }
        int rank   = __popcll(m & ((1ull << lane) - 1ull));
        int myBase = __shfl(base, e);
        int pr     = myBase + rank;
        if (j < Tn) pr1[g * Tn + tok] = pr;
        else        pr2[g * Tn + tok] = pr;
        base += __popcll(mo);
    }
    cnt[g * En + lane] = base;   // == sum_t em_lb[g,t,lane] (counts all, pre-capacity)
}

// ---------------------------------------------------------------------------
// Kernel 5: scatter the <=2 nonzeros per token into dispatch & combine.
// ---------------------------------------------------------------------------
__global__ void k_scatter(const int* __restrict__ e1a, const int* __restrict__ e2a,
                          const float* __restrict__ p1a, const float* __restrict__ p2a,
                          const int* __restrict__ pr1, const int* __restrict__ pr2,
                          float* __restrict__ out)
{
    int tok = blockIdx.x * 256 + threadIdx.x;
    if (tok >= NT) return;
    size_t base = (size_t)tok * En * Cn;
    int p = pr1[tok];
    if (p < Cn) {
        size_t o = base + (size_t)e1a[tok] * Cn + p;
        out[o] = 1.0f;
        out[NDC + o] = p1a[tok];
    }
    p = pr2[tok];
    if (p < Cn) {
        size_t o = base + (size_t)e2a[tok] * Cn + p;
        out[o] = 1.0f;
        out[NDC + o] = p2a[tok];
    }
}

// ---------------------------------------------------------------------------
// Kernel 6: finalize aux_loss and z_loss scalars.
// ---------------------------------------------------------------------------
__global__ __launch_bounds__(256) void k_final(const int* __restrict__ cnt,
                                               const double* __restrict__ sumP,
                                               const double* __restrict__ zsum,
                                               float* __restrict__ out)
{
    __shared__ double red[256];
    int t = threadIdx.x;
    red[t] = (double)cnt[t] * sumP[t];
    __syncthreads();
    for (int s = 128; s; s >>= 1) {
        if (t < s) red[t] += red[t + s];
        __syncthreads();
    }
    if (t == 0) {
        double aux = red[0] * ((double)En / ((double)Gn * (double)Tn * (double)Tn));
        out[2 * NDC]     = (float)aux;
        out[2 * NDC + 1] = (float)(zsum[0] / ((double)Gn * Tn * En));
    }
}

// ---------------------------------------------------------------------------
extern "C" void kernel_launch(void* const* d_in, const int* in_sizes, int n_in,
                              void* d_out, int out_size, void* d_ws, size_t ws_size,
                              hipStream_t stream)
{
    const float* x    = (const float*)d_in[0];   // [G,T,D] fp32
    const float* Wm   = (const float*)d_in[1];   // [D,E] fp32
    const float* bias = (const float*)d_in[2];   // [E] fp32
    float* out = (float*)d_out;

    // workspace carve (all 8-byte aligned in declaration order)
    double* gate = (double*)d_ws;            // NT doubles
    double* sumP = gate + NT;                // G*E doubles
    double* zsum = sumP + Gn * En;           // 1 double
    int* e1a  = (int*)(zsum + 1);            // NT
    int* e2a  = e1a + NT;                    // NT
    int* sidx = e2a + NT;                    // NT
    int* pr1  = sidx + NT;                   // NT
    int* pr2  = pr1 + NT;                    // NT
    int* cnt  = pr2 + NT;                    // G*E
    int* eseq = cnt + Gn * En;               // G*2T
    int* tseq = eseq + Gn * 2 * Tn;          // G*2T
    float* p1a = (float*)(tseq + Gn * 2 * Tn);
    float* p2a = p1a + NT;

    // zero-fill dispatch + combine (1.074 GB) — the write roofline
    hipMemsetAsync(d_out, 0, (size_t)2 * NDC * sizeof(float), stream);

    k_zero<<<1, 256, 0, stream>>>(sumP);                 // sumP + zsum contiguous
    k_gemm<<<NT / 16, 256, 0, stream>>>(x, Wm, bias, gate, e1a, e2a, p1a, p2a,
                                        sumP, zsum);
    k_sort<<<Gn, 1024, 0, stream>>>(gate, sidx);
    k_gather<<<(Gn * 2 * Tn) / 256, 256, 0, stream>>>(sidx, e1a, e2a, eseq, tseq);
    k_prio<<<Gn, 64, 0, stream>>>(eseq, tseq, pr1, pr2, cnt);
    k_scatter<<<NT / 256, 256, 0, stream>>>(e1a, e2a, p1a, p2a, pr1, pr2, out);
    k_final<<<1, 256, 0, stream>>>(cnt, sumP, zsum, out);
}

// Round 2
// 1403.468 us; speedup vs baseline: 1.0237x; 1.0237x over previous
//
#include <hip/hip_runtime.h>

// Problem constants (Switch-Transformer tokens-choose router)
constexpr int Gn = 4;      // groups
constexpr int Tn = 4096;   // tokens per group
constexpr int Dn = 2048;   // d_model
constexpr int En = 64;     // experts
constexpr int Cn = 128;    // expert capacity
constexpr int NT = Gn * Tn;                  // 16384 tokens total
constexpr size_t NDC = (size_t)NT * En * Cn; // 134217728 elements per [g,t,e,c]

// ---------------------------------------------------------------------------
// Kernel 0: zero the fp64 accumulators (sumP[256] + zsum[1])
// ---------------------------------------------------------------------------
__global__ void k_zero(double* acc) {
    int i = threadIdx.x;
    if (i < Gn * En + 1) acc[i] = 0.0;
}

// ---------------------------------------------------------------------------
// Kernel 1 (fused): fp64 router GEMM + softmax + top-2 + stats
//                   + streaming zero-fill of the 1.07 GB output.
// Block = 256 threads = 4 waves; block handles 16 consecutive tokens.
// Wave w: tokens w*4..w*4+3. Lane: ep=lane&31 -> experts {2ep,2ep+1},
//         tp=lane>>5 -> tokens {4w+2tp, 4w+2tp+1}. acc[2][2].
// LDS: xsd[16][64] fp64 (8 KB) + sWd[64][64] fp64 (32 KB) = 40 KB
//      -> 4 blocks/CU; spart/zpart reuse xsd region after the K-loop.
// ---------------------------------------------------------------------------
__global__ __launch_bounds__(256, 4) void k_fused(
    const float* __restrict__ x, const float* __restrict__ Wm,
    const float* __restrict__ bias,
    double* __restrict__ gate, int* __restrict__ e1a, int* __restrict__ e2a,
    float* __restrict__ p1a, float* __restrict__ p2a,
    double* __restrict__ sumP, double* __restrict__ zsum,
    float* __restrict__ outz)
{
    __shared__ double smem[16 * 64 + 64 * 64];   // xsd | sWd
    double* xsd = smem;                           // [16][64]
    double (*sWd)[64] = (double(*)[64])(smem + 16 * 64);

    const int tid  = threadIdx.x;
    const int lane = tid & 63;
    const int wave = tid >> 6;
    const int ep   = lane & 31;
    const int tp   = lane >> 5;
    const int tok0 = blockIdx.x * 16;
    const int g    = blockIdx.x >> 8;   // 256 blocks per group

    // zero-fill base for this block: 1 MB = 65536 float4
    float4* zbase = (float4*)outz + (size_t)blockIdx.x * 65536;
    const float4 z4 = make_float4(0.f, 0.f, 0.f, 0.f);

    double a00 = 0.0, a01 = 0.0, a10 = 0.0, a11 = 0.0;

    const int xrow0 = wave * 4 + tp * 2;

    for (int it = 0; it < 32; ++it) {
        const int d0 = it * 64;
        // ---- stage x tile as fp64: 16 tokens x 64 dims ----
        {
            int row = tid >> 4;
            int col = (tid & 15) * 4;
            float4 v = *(const float4*)(x + (size_t)(tok0 + row) * Dn + d0 + col);
            double* p = &xsd[row * 64 + col];
            *(double2*)(p)     = double2{(double)v.x, (double)v.y};
            *(double2*)(p + 2) = double2{(double)v.z, (double)v.w};
        }
        // ---- stage W tile as fp64: rows d0..d0+63, 64 experts ----
        {
            int k  = tid >> 2;
            int e0 = (tid & 3) * 16;
            const float4* src = (const float4*)(Wm + (size_t)(d0 + k) * En + e0);
            #pragma unroll
            for (int u = 0; u < 4; ++u) {
                float4 v = src[u];
                double* p = &sWd[k][e0 + 4 * u];
                *(double2*)(p)     = double2{(double)v.x, (double)v.y};
                *(double2*)(p + 2) = double2{(double)v.z, (double)v.w};
            }
        }
        // ---- streaming zero-fill: 32 KB per block per iter ----
        {
            float4* dst = zbase + it * 2048;
            #pragma unroll
            for (int u = 0; u < 8; ++u) dst[tid + 256 * u] = z4;
        }
        __syncthreads();

        // ---- fp64 compute: 2 tokens x 2 experts per lane ----
        const double* xr0 = &xsd[xrow0 * 64];
        const double* xr1 = &xsd[(xrow0 + 1) * 64];
        #pragma unroll 4
        for (int k2 = 0; k2 < 32; ++k2) {
            double2 xa = *(const double2*)&xr0[2 * k2];
            double2 xb = *(const double2*)&xr1[2 * k2];
            double2 w0 = *(const double2*)&sWd[2 * k2][2 * ep];
            double2 w1 = *(const double2*)&sWd[2 * k2 + 1][2 * ep];
            a00 += xa.x * w0.x; a01 += xa.x * w0.y;
            a00 += xa.y * w1.x; a01 += xa.y * w1.y;
            a10 += xb.x * w0.x; a11 += xb.x * w0.y;
            a10 += xb.y * w1.x; a11 += xb.y * w1.y;
        }
        __syncthreads();
    }

    // ---------------- epilogue ----------------
    const double bl0 = (double)bias[2 * ep];
    const double bl1 = (double)bias[2 * ep + 1];
    double sp0 = 0.0, sp1 = 0.0, zhalf = 0.0;

    #pragma unroll
    for (int tl = 0; tl < 2; ++tl) {
        double l0 = (tl == 0 ? a00 : a10) + bl0;
        double l1 = (tl == 0 ? a01 : a11) + bl1;
        // half-wave (32-lane) reductions: offsets 16..1 stay within the half
        double m = fmax(l0, l1);
        #pragma unroll
        for (int off = 16; off; off >>= 1) {
            double o = __shfl_xor(m, off);
            m = fmax(m, o);
        }
        double ex0 = exp(l0 - m), ex1 = exp(l1 - m);
        double s = ex0 + ex1;
        #pragma unroll
        for (int off = 16; off; off >>= 1) s += __shfl_xor(s, off);
        double p0 = ex0 / s, p1 = ex1 / s;
        double lse = m + log(s);
        double z = (l0 - lse) * (l0 - lse) + (l1 - lse) * (l1 - lse);
        #pragma unroll
        for (int off = 16; off; off >>= 1) z += __shfl_xor(z, off);
        zhalf += z;
        sp0 += p0; sp1 += p1;

        // top-2 across 64 experts (2 local + 32-lane butterfly merge)
        double av, bv; int ai, bi;
        if (p0 >= p1) { av = p0; ai = 2 * ep;     bv = p1; bi = 2 * ep + 1; }
        else          { av = p1; ai = 2 * ep + 1; bv = p0; bi = 2 * ep;     }
        #pragma unroll
        for (int off = 16; off; off >>= 1) {
            double av2 = __shfl_xor(av, off); int ai2 = __shfl_xor(ai, off);
            double bv2 = __shfl_xor(bv, off); int bi2 = __shfl_xor(bi, off);
            bool aWins = (av > av2) || (av == av2 && ai < ai2);
            if (aWins) {
                bool t = (bv > av2) || (bv == av2 && bi < ai2);
                if (!t) { bv = av2; bi = ai2; }
            } else {
                bool t = (av > bv2) || (av == bv2 && ai < bi2);
                if (t) { bv = av; bi = ai; }
                else   { bv = bv2; bi = bi2; }
                av = av2; ai = ai2;
            }
        }
        if (ep == 0) {
            int tok = tok0 + wave * 4 + tp * 2 + tl;
            gate[tok] = av;
            e1a[tok] = ai;
            e2a[tok] = bi;
            p1a[tok] = (float)av;
            p2a[tok] = (float)bv;
        }
    }

    // combine halves for per-expert prob sums (4 tokens of this wave)
    sp0 += __shfl_xor(sp0, 32);
    sp1 += __shfl_xor(sp1, 32);

    // reuse xsd region (dead after K-loop) for block reductions
    double* spart = smem;         // [wave*64 + e]
    double* zpart = smem + 256;   // [wave*2 + tp]
    if (tp == 0) {
        spart[wave * 64 + 2 * ep]     = sp0;
        spart[wave * 64 + 2 * ep + 1] = sp1;
    }
    if (ep == 0) zpart[wave * 2 + tp] = zhalf;
    __syncthreads();
    if (wave == 0) {
        double v = spart[lane] + spart[64 + lane] + spart[128 + lane] + spart[192 + lane];
        atomicAdd(&sumP[g * En + lane], v);
        if (lane == 0) {
            double zz = 0.0;
            #pragma unroll
            for (int w = 0; w < 8; ++w) zz += zpart[w];
            atomicAdd(zsum, zz);
        }
    }
}

// ---------------------------------------------------------------------------
// Kernel 2: per-group bitonic sort of 4096 tokens by (gate desc, idx asc).
// ---------------------------------------------------------------------------
__global__ __launch_bounds__(1024) void k_sort(const double* __restrict__ gate,
                                               int* __restrict__ sidx)
{
    __shared__ double key[4096];
    __shared__ int    val[4096];
    const int g = blockIdx.x;
    for (int i = threadIdx.x; i < Tn; i += 1024) {
        key[i] = gate[g * Tn + i];
        val[i] = i;
    }
    __syncthreads();
    for (int k = 2; k <= Tn; k <<= 1) {
        for (int j = k >> 1; j > 0; j >>= 1) {
            for (int i = threadIdx.x; i < Tn; i += 1024) {
                int ixj = i ^ j;
                if (ixj > i) {
                    bool dir = ((i & k) == 0);
                    double ka = key[i], kb = key[ixj];
                    int    va = val[i], vb = val[ixj];
                    bool bFirst = (kb > ka) || (kb == ka && vb < va);
                    if (bFirst == dir) {
                        key[i] = kb; key[ixj] = ka;
                        val[i] = vb; val[ixj] = va;
                    }
                }
            }
            __syncthreads();
        }
    }
    for (int i = threadIdx.x; i < Tn; i += 1024) sidx[g * Tn + i] = val[i];
}

// ---------------------------------------------------------------------------
// Kernel 3: gather expert sequence in cumsum order (top-1 block then top-2).
// ---------------------------------------------------------------------------
__global__ void k_gather(const int* __restrict__ sidx,
                         const int* __restrict__ e1a, const int* __restrict__ e2a,
                         int* __restrict__ eseq, int* __restrict__ tseq)
{
    int idx = blockIdx.x * 256 + threadIdx.x;   // 0 .. 32767
    int g = idx >> 13;
    int j = idx & 8191;
    int s = (j < Tn) ? j : j - Tn;
    int tok = sidx[g * Tn + s];
    int e = (j < Tn) ? e1a[g * Tn + tok] : e2a[g * Tn + tok];
    eseq[idx] = e;
    tseq[idx] = tok;
}

// ---------------------------------------------------------------------------
// Kernel 4: sequential capacity assignment. One wave per group.
// ---------------------------------------------------------------------------
__global__ __launch_bounds__(64) void k_prio(
    const int* __restrict__ eseq, const int* __restrict__ tseq,
    int* __restrict__ pr1, int* __restrict__ pr2, int* __restrict__ cnt)
{
    const int g = blockIdx.x;
    const int lane = threadIdx.x;
    int base = 0;   // running count for expert == lane

    for (int c = 0; c < 2 * Tn / 64; ++c) {
        int j   = c * 64 + lane;
        int e   = eseq[g * 2 * Tn + j];
        int tok = tseq[g * 2 * Tn + j];

        unsigned long long m  = ~0ull;
        unsigned long long mo = ~0ull;
        #pragma unroll
        for (int bb = 0; bb < 6; ++bb) {
            unsigned long long bal = __ballot((e >> bb) & 1);
            m  &= ((e    >> bb) & 1) ? bal : ~bal;
            mo &= ((lane >> bb) & 1) ? bal : ~bal;
        }
        int rank   = __popcll(m & ((1ull << lane) - 1ull));
        int myBase = __shfl(base, e);
        int pr     = myBase + rank;
        if (j < Tn) pr1[g * Tn + tok] = pr;
        else        pr2[g * Tn + tok] = pr;
        base += __popcll(mo);
    }
    cnt[g * En + lane] = base;
}

// ---------------------------------------------------------------------------
// Kernel 5: scatter the <=2 nonzeros per token into dispatch & combine.
// ---------------------------------------------------------------------------
__global__ void k_scatter(const int* __restrict__ e1a, const int* __restrict__ e2a,
                          const float* __restrict__ p1a, const float* __restrict__ p2a,
                          const int* __restrict__ pr1, const int* __restrict__ pr2,
                          float* __restrict__ out)
{
    int tok = blockIdx.x * 256 + threadIdx.x;
    if (tok >= NT) return;
    size_t base = (size_t)tok * En * Cn;
    int p = pr1[tok];
    if (p < Cn) {
        size_t o = base + (size_t)e1a[tok] * Cn + p;
        out[o] = 1.0f;
        out[NDC + o] = p1a[tok];
    }
    p = pr2[tok];
    if (p < Cn) {
        size_t o = base + (size_t)e2a[tok] * Cn + p;
        out[o] = 1.0f;
        out[NDC + o] = p2a[tok];
    }
}

// ---------------------------------------------------------------------------
// Kernel 6: finalize aux_loss and z_loss scalars.
// ---------------------------------------------------------------------------
__global__ __launch_bounds__(256) void k_final(const int* __restrict__ cnt,
                                               const double* __restrict__ sumP,
                                               const double* __restrict__ zsum,
                                               float* __restrict__ out)
{
    __shared__ double red[256];
    int t = threadIdx.x;
    red[t] = (double)cnt[t] * sumP[t];
    __syncthreads();
    for (int s = 128; s; s >>= 1) {
        if (t < s) red[t] += red[t + s];
        __syncthreads();
    }
    if (t == 0) {
        double aux = red[0] * ((double)En / ((double)Gn * (double)Tn * (double)Tn));
        out[2 * NDC]     = (float)aux;
        out[2 * NDC + 1] = (float)(zsum[0] / ((double)Gn * Tn * En));
    }
}

// ---------------------------------------------------------------------------
extern "C" void kernel_launch(void* const* d_in, const int* in_sizes, int n_in,
                              void* d_out, int out_size, void* d_ws, size_t ws_size,
                              hipStream_t stream)
{
    const float* x    = (const float*)d_in[0];   // [G,T,D] fp32
    const float* Wm   = (const float*)d_in[1];   // [D,E] fp32
    const float* bias = (const float*)d_in[2];   // [E] fp32
    float* out = (float*)d_out;

    // workspace carve (8-byte aligned in declaration order)
    double* gate = (double*)d_ws;            // NT doubles
    double* sumP = gate + NT;                // G*E doubles
    double* zsum = sumP + Gn * En;           // 1 double
    int* e1a  = (int*)(zsum + 1);            // NT
    int* e2a  = e1a + NT;                    // NT
    int* sidx = e2a + NT;                    // NT
    int* pr1  = sidx + NT;                   // NT
    int* pr2  = pr1 + NT;                    // NT
    int* cnt  = pr2 + NT;                    // G*E
    int* eseq = cnt + Gn * En;               // G*2T
    int* tseq = eseq + Gn * 2 * Tn;          // G*2T
    float* p1a = (float*)(tseq + Gn * 2 * Tn);
    float* p2a = p1a + NT;

    k_zero<<<1, 256, 0, stream>>>(sumP);     // sumP + zsum contiguous

    // fused GEMM + epilogue + zero-fill of the full 1.07 GB output
    k_fused<<<NT / 16, 256, 0, stream>>>(x, Wm, bias, gate, e1a, e2a, p1a, p2a,
                                         sumP, zsum, out);

    k_sort<<<Gn, 1024, 0, stream>>>(gate, sidx);
    k_gather<<<(Gn * 2 * Tn) / 256, 256, 0, stream>>>(sidx, e1a, e2a, eseq, tseq);
    k_prio<<<Gn, 64, 0, stream>>>(eseq, tseq, pr1, pr2, cnt);
    k_scatter<<<NT / 256, 256, 0, stream>>>(e1a, e2a, p1a, p2a, pr1, pr2, out);
    k_final<<<1, 256, 0, stream>>>(cnt, sumP, zsum, out);
}

// Round 3
// 1379.718 us; speedup vs baseline: 1.0413x; 1.0172x over previous
//
#include <hip/hip_runtime.h>

// Problem constants (Switch-Transformer tokens-choose router)
constexpr int Gn = 4;      // groups
constexpr int Tn = 4096;   // tokens per group
constexpr int Dn = 2048;   // d_model
constexpr int En = 64;     // experts
constexpr int Cn = 128;    // expert capacity
constexpr int NT = Gn * Tn;                  // 16384 tokens total
constexpr size_t NDC = (size_t)NT * En * Cn; // 134217728 elements per [g,t,e,c]

// ---------------------------------------------------------------------------
// Kernel 0: zero the fp64 accumulators (sumP[256] + zsum[1])
// ---------------------------------------------------------------------------
__global__ void k_zero(double* acc) {
    int i = threadIdx.x;
    if (i < Gn * En + 1) acc[i] = 0.0;
}

// ---------------------------------------------------------------------------
// Kernel 1: fp64 router GEMM + softmax + top-2 + stats.
// 256 blocks x 256 threads. Block: 64 tokens x 64 experts, K-tiles of 64.
// Per-lane 4 tokens x 4 experts fp64 acc (er = lane&15 -> experts 4er..4er+3,
// tr = lane>>4; token base = wave*16 + tr*4).
// LDS holds fp32 tiles (xs transposed [k][tok] pad 68, ws [k][e]); operands
// cvt to fp64 after load -> 2 B LDS per MAC, FMA-floor-bound (~55us aggregate).
// Register double-buffer: next tile's global loads fly during compute.
// ---------------------------------------------------------------------------
__global__ __launch_bounds__(256) void k_gemm(
    const float* __restrict__ x, const float* __restrict__ Wm,
    const float* __restrict__ bias,
    double* __restrict__ gate, int* __restrict__ e1a, int* __restrict__ e2a,
    float* __restrict__ p1a, float* __restrict__ p2a,
    double* __restrict__ sumP, double* __restrict__ zsum)
{
    __shared__ double smem_d[4224];              // 33792 B, reused for stats
    float* xs = (float*)smem_d;                  // [64][68] fp32 (transposed)
    float* ws = (float*)smem_d + 64 * 68;        // [64][64] fp32

    const int tid  = threadIdx.x;
    const int lane = tid & 63;
    const int wave = tid >> 6;
    const int er   = lane & 15;      // expert quad: experts 4er..4er+3
    const int tr   = lane >> 4;      // token quad within wave
    const int tok0 = blockIdx.x * 64;
    const int g    = blockIdx.x >> 6;   // 64 blocks per group

    // staging mapping: kq = k-float4 within tile, tg = token group
    const int kq = tid & 15;
    const int tg = tid >> 4;

    double acc[4][4];
    #pragma unroll
    for (int i = 0; i < 4; ++i)
        #pragma unroll
        for (int j = 0; j < 4; ++j) acc[i][j] = 0.0;

    float4 px[4], pw[4];
    // prefetch tile 0
    #pragma unroll
    for (int j = 0; j < 4; ++j)
        px[j] = *(const float4*)(x + (size_t)(tok0 + tg * 4 + j) * Dn + 4 * kq);
    #pragma unroll
    for (int j = 0; j < 4; ++j)
        pw[j] = ((const float4*)Wm)[tid + 256 * j];

    const int tb = wave * 16 + tr * 4;   // token base for this lane
    const float* xsp = xs + tb;
    const float* wsp = ws + 4 * er;

    for (int it = 0; it < 32; ++it) {
        // commit prefetched regs to LDS (x transposed)
        #pragma unroll
        for (int j = 0; j < 4; ++j) {
            const float* pf = (const float*)&px[j];
            #pragma unroll
            for (int jj = 0; jj < 4; ++jj)
                xs[(4 * kq + jj) * 68 + tg * 4 + j] = pf[jj];
        }
        #pragma unroll
        for (int j = 0; j < 4; ++j)
            ((float4*)ws)[tid + 256 * j] = pw[j];
        __syncthreads();

        // prefetch next tile (completes during compute below)
        if (it < 31) {
            const int k0 = (it + 1) * 64;
            #pragma unroll
            for (int j = 0; j < 4; ++j)
                px[j] = *(const float4*)(x + (size_t)(tok0 + tg * 4 + j) * Dn + k0 + 4 * kq);
            #pragma unroll
            for (int j = 0; j < 4; ++j)
                pw[j] = ((const float4*)(Wm + (size_t)k0 * En))[tid + 256 * j];
        }

        // compute: 64 k-steps, 16 fp64 FMAs each
        #pragma unroll 4
        for (int k = 0; k < 64; ++k) {
            float4 xf = *(const float4*)(xsp + 68 * k);
            float4 wf = *(const float4*)(wsp + 64 * k);
            double xd0 = (double)xf.x, xd1 = (double)xf.y;
            double xd2 = (double)xf.z, xd3 = (double)xf.w;
            double wd0 = (double)wf.x, wd1 = (double)wf.y;
            double wd2 = (double)wf.z, wd3 = (double)wf.w;
            acc[0][0] += xd0 * wd0; acc[0][1] += xd0 * wd1;
            acc[0][2] += xd0 * wd2; acc[0][3] += xd0 * wd3;
            acc[1][0] += xd1 * wd0; acc[1][1] += xd1 * wd1;
            acc[1][2] += xd1 * wd2; acc[1][3] += xd1 * wd3;
            acc[2][0] += xd2 * wd0; acc[2][1] += xd2 * wd1;
            acc[2][2] += xd2 * wd2; acc[2][3] += xd2 * wd3;
            acc[3][0] += xd3 * wd0; acc[3][1] += xd3 * wd1;
            acc[3][2] += xd3 * wd2; acc[3][3] += xd3 * wd3;
        }
        __syncthreads();
    }

    // ---------------- epilogue: softmax + top-2 + stats ----------------
    const double b0 = (double)bias[4 * er + 0];
    const double b1 = (double)bias[4 * er + 1];
    const double b2 = (double)bias[4 * er + 2];
    const double b3 = (double)bias[4 * er + 3];
    double sp[4] = {0.0, 0.0, 0.0, 0.0};
    double zpart = 0.0;

    #pragma unroll
    for (int i = 0; i < 4; ++i) {
        double l0 = acc[i][0] + b0, l1 = acc[i][1] + b1;
        double l2 = acc[i][2] + b2, l3 = acc[i][3] + b3;
        double m = fmax(fmax(l0, l1), fmax(l2, l3));
        #pragma unroll
        for (int off = 8; off; off >>= 1) m = fmax(m, __shfl_xor(m, off));
        double e0v = exp(l0 - m), e1v = exp(l1 - m);
        double e2v = exp(l2 - m), e3v = exp(l3 - m);
        double s = e0v + e1v + e2v + e3v;
        #pragma unroll
        for (int off = 8; off; off >>= 1) s += __shfl_xor(s, off);
        double inv = 1.0 / s;
        double p0 = e0v * inv, p1 = e1v * inv, p2 = e2v * inv, p3 = e3v * inv;
        sp[0] += p0; sp[1] += p1; sp[2] += p2; sp[3] += p3;
        double lse = m + log(s);
        double z = (l0 - lse) * (l0 - lse) + (l1 - lse) * (l1 - lse)
                 + (l2 - lse) * (l2 - lse) + (l3 - lse) * (l3 - lse);
        #pragma unroll
        for (int off = 8; off; off >>= 1) z += __shfl_xor(z, off);
        zpart += z;

        // local top-2 over the 4 owned experts (ties -> lower index)
        double av, bv; int ai, bi;
        if (p1 > p0) { av = p1; ai = 4 * er + 1; bv = p0; bi = 4 * er; }
        else         { av = p0; ai = 4 * er;     bv = p1; bi = 4 * er + 1; }
        if (p2 > av)      { bv = av; bi = ai; av = p2; ai = 4 * er + 2; }
        else if (p2 > bv) { bv = p2; bi = 4 * er + 2; }
        if (p3 > av)      { bv = av; bi = ai; av = p3; ai = 4 * er + 3; }
        else if (p3 > bv) { bv = p3; bi = 4 * er + 3; }

        // butterfly merge across the 16 er-lanes
        #pragma unroll
        for (int off = 8; off; off >>= 1) {
            double av2 = __shfl_xor(av, off); int ai2 = __shfl_xor(ai, off);
            double bv2 = __shfl_xor(bv, off); int bi2 = __shfl_xor(bi, off);
            bool aWins = (av > av2) || (av == av2 && ai < ai2);
            if (aWins) {
                bool t = (bv > av2) || (bv == av2 && bi < ai2);
                if (!t) { bv = av2; bi = ai2; }
            } else {
                bool t = (av > bv2) || (av == bv2 && ai < bi2);
                if (t) { bv = av; bi = ai; }
                else   { bv = bv2; bi = bi2; }
                av = av2; ai = ai2;
            }
        }
        if (er == 0) {
            int tok = tok0 + tb + i;
            gate[tok] = av;
            e1a[tok] = ai;
            e2a[tok] = bi;
            p1a[tok] = (float)av;
            p2a[tok] = (float)bv;
        }
    }

    // block-level stats reduction (reuse smem, all waves past last barrier)
    double* sp_sm = smem_d;          // [16][64]
    double* z_sm  = smem_d + 16 * 64;
    const int r = wave * 4 + tr;
    #pragma unroll
    for (int j = 0; j < 4; ++j) sp_sm[r * 64 + 4 * er + j] = sp[j];
    if (er == 0) z_sm[r] = zpart;
    __syncthreads();
    if (wave == 0) {
        double v = 0.0;
        #pragma unroll
        for (int r2 = 0; r2 < 16; ++r2) v += sp_sm[r2 * 64 + lane];
        atomicAdd(&sumP[g * En + lane], v);
        if (lane == 0) {
            double zz = 0.0;
            #pragma unroll
            for (int r2 = 0; r2 < 16; ++r2) zz += z_sm[r2];
            atomicAdd(zsum, zz);
        }
    }
}

// ---------------------------------------------------------------------------
// Kernel 2: blocks 0..3 = per-group bitonic sort of 4096 tokens by
// (gate desc, idx asc); blocks 4..1027 = zero-fill 1 MB each of the
// 1.07 GB output (overlaps the otherwise-idle GPU during the sort).
// ---------------------------------------------------------------------------
__global__ __launch_bounds__(1024) void k_sortfill(const double* __restrict__ gate,
                                                   int* __restrict__ sidx,
                                                   float4* __restrict__ outz)
{
    __shared__ double key[4096];
    __shared__ int    val[4096];

    if (blockIdx.x >= 4) {
        // zero-fill: 65536 float4 per block
        float4* dst = outz + (size_t)(blockIdx.x - 4) * 65536;
        const float4 z4 = make_float4(0.f, 0.f, 0.f, 0.f);
        #pragma unroll 8
        for (int u = 0; u < 64; ++u) dst[threadIdx.x + 1024 * u] = z4;
        return;
    }

    const int g = blockIdx.x;
    for (int i = threadIdx.x; i < Tn; i += 1024) {
        key[i] = gate[g * Tn + i];
        val[i] = i;
    }
    __syncthreads();
    for (int k = 2; k <= Tn; k <<= 1) {
        for (int j = k >> 1; j > 0; j >>= 1) {
            for (int i = threadIdx.x; i < Tn; i += 1024) {
                int ixj = i ^ j;
                if (ixj > i) {
                    bool dir = ((i & k) == 0);
                    double ka = key[i], kb = key[ixj];
                    int    va = val[i], vb = val[ixj];
                    bool bFirst = (kb > ka) || (kb == ka && vb < va);
                    if (bFirst == dir) {
                        key[i] = kb; key[ixj] = ka;
                        val[i] = vb; val[ixj] = va;
                    }
                }
            }
            __syncthreads();
        }
    }
    for (int i = threadIdx.x; i < Tn; i += 1024) sidx[g * Tn + i] = val[i];
}

// ---------------------------------------------------------------------------
// Kernel 3: gather expert sequence in cumsum order (top-1 block then top-2).
// ---------------------------------------------------------------------------
__global__ void k_gather(const int* __restrict__ sidx,
                         const int* __restrict__ e1a, const int* __restrict__ e2a,
                         int* __restrict__ eseq, int* __restrict__ tseq)
{
    int idx = blockIdx.x * 256 + threadIdx.x;   // 0 .. 32767
    int g = idx >> 13;
    int j = idx & 8191;
    int s = (j < Tn) ? j : j - Tn;
    int tok = sidx[g * Tn + s];
    int e = (j < Tn) ? e1a[g * Tn + tok] : e2a[g * Tn + tok];
    eseq[idx] = e;
    tseq[idx] = tok;
}

// ---------------------------------------------------------------------------
// Kernel 4: sequential capacity assignment. One wave per group.
// ---------------------------------------------------------------------------
__global__ __launch_bounds__(64) void k_prio(
    const int* __restrict__ eseq, const int* __restrict__ tseq,
    int* __restrict__ pr1, int* __restrict__ pr2, int* __restrict__ cnt)
{
    const int g = blockIdx.x;
    const int lane = threadIdx.x;
    int base = 0;   // running count for expert == lane

    for (int c = 0; c < 2 * Tn / 64; ++c) {
        int j   = c * 64 + lane;
        int e   = eseq[g * 2 * Tn + j];
        int tok = tseq[g * 2 * Tn + j];

        unsigned long long m  = ~0ull;
        unsigned long long mo = ~0ull;
        #pragma unroll
        for (int bb = 0; bb < 6; ++bb) {
            unsigned long long bal = __ballot((e >> bb) & 1);
            m  &= ((e    >> bb) & 1) ? bal : ~bal;
            mo &= ((lane >> bb) & 1) ? bal : ~bal;
        }
        int rank   = __popcll(m & ((1ull << lane) - 1ull));
        int myBase = __shfl(base, e);
        int pr     = myBase + rank;
        if (j < Tn) pr1[g * Tn + tok] = pr;
        else        pr2[g * Tn + tok] = pr;
        base += __popcll(mo);
    }
    cnt[g * En + lane] = base;
}

// ---------------------------------------------------------------------------
// Kernel 5: scatter the <=2 nonzeros per token into dispatch & combine.
// ---------------------------------------------------------------------------
__global__ void k_scatter(const int* __restrict__ e1a, const int* __restrict__ e2a,
                          const float* __restrict__ p1a, const float* __restrict__ p2a,
                          const int* __restrict__ pr1, const int* __restrict__ pr2,
                          float* __restrict__ out)
{
    int tok = blockIdx.x * 256 + threadIdx.x;
    if (tok >= NT) return;
    size_t base = (size_t)tok * En * Cn;
    int p = pr1[tok];
    if (p < Cn) {
        size_t o = base + (size_t)e1a[tok] * Cn + p;
        out[o] = 1.0f;
        out[NDC + o] = p1a[tok];
    }
    p = pr2[tok];
    if (p < Cn) {
        size_t o = base + (size_t)e2a[tok] * Cn + p;
        out[o] = 1.0f;
        out[NDC + o] = p2a[tok];
    }
}

// ---------------------------------------------------------------------------
// Kernel 6: finalize aux_loss and z_loss scalars.
// ---------------------------------------------------------------------------
__global__ __launch_bounds__(256) void k_final(const int* __restrict__ cnt,
                                               const double* __restrict__ sumP,
                                               const double* __restrict__ zsum,
                                               float* __restrict__ out)
{
    __shared__ double red[256];
    int t = threadIdx.x;
    red[t] = (double)cnt[t] * sumP[t];
    __syncthreads();
    for (int s = 128; s; s >>= 1) {
        if (t < s) red[t] += red[t + s];
        __syncthreads();
    }
    if (t == 0) {
        double aux = red[0] * ((double)En / ((double)Gn * (double)Tn * (double)Tn));
        out[2 * NDC]     = (float)aux;
        out[2 * NDC + 1] = (float)(zsum[0] / ((double)Gn * Tn * En));
    }
}

// ---------------------------------------------------------------------------
extern "C" void kernel_launch(void* const* d_in, const int* in_sizes, int n_in,
                              void* d_out, int out_size, void* d_ws, size_t ws_size,
                              hipStream_t stream)
{
    const float* x    = (const float*)d_in[0];   // [G,T,D] fp32
    const float* Wm   = (const float*)d_in[1];   // [D,E] fp32
    const float* bias = (const float*)d_in[2];   // [E] fp32
    float* out = (float*)d_out;

    // workspace carve (8-byte aligned in declaration order)
    double* gate = (double*)d_ws;            // NT doubles
    double* sumP = gate + NT;                // G*E doubles
    double* zsum = sumP + Gn * En;           // 1 double
    int* e1a  = (int*)(zsum + 1);            // NT
    int* e2a  = e1a + NT;                    // NT
    int* sidx = e2a + NT;                    // NT
    int* pr1  = sidx + NT;                   // NT
    int* pr2  = pr1 + NT;                    // NT
    int* cnt  = pr2 + NT;                    // G*E
    int* eseq = cnt + Gn * En;               // G*2T
    int* tseq = eseq + Gn * 2 * Tn;          // G*2T
    float* p1a = (float*)(tseq + Gn * 2 * Tn);
    float* p2a = p1a + NT;

    k_zero<<<1, 256, 0, stream>>>(sumP);     // sumP + zsum contiguous

    k_gemm<<<256, 256, 0, stream>>>(x, Wm, bias, gate, e1a, e2a, p1a, p2a,
                                    sumP, zsum);
    // sort (4 blocks) + zero-fill of 1.07 GB output (1024 blocks), overlapped
    k_sortfill<<<1028, 1024, 0, stream>>>(gate, sidx, (float4*)out);
    k_gather<<<(Gn * 2 * Tn) / 256, 256, 0, stream>>>(sidx, e1a, e2a, eseq, tseq);
    k_prio<<<Gn, 64, 0, stream>>>(eseq, tseq, pr1, pr2, cnt);
    k_scatter<<<NT / 256, 256, 0, stream>>>(e1a, e2a, p1a, p2a, pr1, pr2, out);
    k_final<<<1, 256, 0, stream>>>(cnt, sumP, zsum, out);
}